// Round 10
// baseline (479.230 us; speedup 1.0000x reference)
//
#include <hip/hip_runtime.h>
#include <math.h>

#define WAVE 64

__device__ inline float wave_reduce_sum(float v) {
    #pragma unroll
    for (int off = 32; off > 0; off >>= 1)
        v += __shfl_xor(v, off, WAVE);
    return v;
}

// ---------- fp8 e4m3fn helpers ----------
__device__ inline unsigned int f32_to_e4m3(float a) {
    unsigned int u = __float_as_uint(a);
    unsigned int sgn = (u >> 31) << 7;
    unsigned int absu = u & 0x7FFFFFFFu;
    if (absu < 0x3C800000u) return sgn;            // |a| < 2^-6 -> signed zero
    int exp = (int)(absu >> 23) - 127;
    unsigned int m = absu & 0x7FFFFFu;
    unsigned int keep = m >> 20;
    unsigned int rest = m & 0xFFFFFu;
    if (rest > 0x80000u || (rest == 0x80000u && (keep & 1u))) keep++;
    if (keep == 8u) { keep = 0u; exp += 1; }
    if (exp > 8) { exp = 8; keep = 7u; }           // clamp (safety)
    return sgn | ((unsigned int)(exp + 7) << 3) | keep;
}

__device__ inline float e4m3_to_f32(unsigned int b) {
    unsigned int expm = b & 0x7Fu;
    unsigned int f = ((b & 0x80u) << 24) | ((expm + (120u << 3)) << 20);
    float v = __uint_as_float(f);
    return (expm & 0x78u) ? v : 0.0f;
}

__device__ inline void decode4_fp8(unsigned int u, float& a, float& b, float& c, float& d) {
#if __has_builtin(__builtin_amdgcn_cvt_pk_f32_fp8)
    auto lo = __builtin_amdgcn_cvt_pk_f32_fp8(u, false);
    auto hi = __builtin_amdgcn_cvt_pk_f32_fp8(u, true);
    a = lo[0]; b = lo[1]; c = hi[0]; d = hi[1];
#else
    a = e4m3_to_f32(u & 0xFFu);
    b = e4m3_to_f32((u >> 8) & 0xFFu);
    c = e4m3_to_f32((u >> 16) & 0xFFu);
    d = e4m3_to_f32((u >> 24) & 0xFFu);
#endif
}

// Convert f32 array to packed fp8 with pre-scale. n4 = n/4 uints out.
__global__ void cvt_fp8_kernel(const float* __restrict__ in,
                               unsigned int* __restrict__ out,
                               int n4, float scale) {
    int i = blockIdx.x * blockDim.x + threadIdx.x;
    if (i >= n4) return;
    float4 v = ((const float4*)in)[i];
    unsigned int b0 = f32_to_e4m3(v.x * scale);
    unsigned int b1 = f32_to_e4m3(v.y * scale);
    unsigned int b2 = f32_to_e4m3(v.z * scale);
    unsigned int b3 = f32_to_e4m3(v.w * scale);
    out[i] = b0 | (b1 << 8) | (b2 << 16) | (b3 << 24);
}

// Kernel 1: per-entity  ew[i] = dot(start_emb[i], W0) + dot(prompt_emb[i], W1)
__global__ void entity_dots_kernel(const float* __restrict__ start_emb,
                                   const float* __restrict__ prompt_emb,
                                   const float* __restrict__ W,
                                   float* __restrict__ ew, int N, int D) {
    int wavesPerBlock = blockDim.x >> 6;
    int i = blockIdx.x * wavesPerBlock + (threadIdx.x >> 6);
    int lane = threadIdx.x & 63;
    if (i >= N) return;
    const float* s  = start_emb  + (size_t)i * D;
    const float* p  = prompt_emb + (size_t)i * D;
    const float* w0 = W;
    const float* w1 = W + D;
    float acc = 0.f;
    for (int idx = lane * 4; idx < D; idx += WAVE * 4) {
        float4 sv  = *(const float4*)(s  + idx);
        float4 pv  = *(const float4*)(p  + idx);
        float4 w0v = *(const float4*)(w0 + idx);
        float4 w1v = *(const float4*)(w1 + idx);
        acc = fmaf(sv.x, w0v.x, acc);
        acc = fmaf(sv.y, w0v.y, acc);
        acc = fmaf(sv.z, w0v.z, acc);
        acc = fmaf(sv.w, w0v.w, acc);
        acc = fmaf(pv.x, w1v.x, acc);
        acc = fmaf(pv.y, w1v.y, acc);
        acc = fmaf(pv.z, w1v.z, acc);
        acc = fmaf(pv.w, w1v.w, acc);
    }
    acc = wave_reduce_sum(acc);
    if (lane == 0) ew[i] = acc;
}

// ---------- counting-sort of relations by counts[] ----------
// init: zero segs/sege (M) and hist (VOCAB)
__global__ void init_kernel(int* __restrict__ segs, int* __restrict__ sege,
                            int* __restrict__ hist, int M, int V) {
    int i = blockIdx.x * blockDim.x + threadIdx.x;
    if (i < M) { segs[i] = 0; sege[i] = 0; }
    if (i < V) hist[i] = 0;
}

__global__ void hist_kernel(const int* __restrict__ counts,
                            int* __restrict__ hist, int R) {
    int r = blockIdx.x * blockDim.x + threadIdx.x;
    if (r < R) atomicAdd(&hist[counts[r]], 1);
}

// single-block exclusive scan: hist[V] -> binpos[V]
__global__ __launch_bounds__(1024) void scan_kernel(const int* __restrict__ hist,
                                                    int* __restrict__ binpos, int V) {
    __shared__ int partial[1024];
    int t = threadIdx.x;
    int per = (V + 1023) / 1024;
    int base = t * per;
    int lim = base + per; if (lim > V) lim = V;
    int sum = 0;
    for (int i = base; i < lim; ++i) sum += hist[i];
    partial[t] = sum;
    __syncthreads();
    for (int ofs = 1; ofs < 1024; ofs <<= 1) {
        int v = (t >= ofs) ? partial[t - ofs] : 0;
        __syncthreads();
        partial[t] += v;
        __syncthreads();
    }
    int run = (t == 0) ? 0 : partial[t - 1];
    for (int i = base; i < lim; ++i) {
        binpos[i] = run;
        run += hist[i];
    }
}

__global__ void scatter_kernel(const int* __restrict__ counts,
                               int* __restrict__ binpos,
                               int* __restrict__ perm, int R) {
    int r = blockIdx.x * blockDim.x + threadIdx.x;
    if (r >= R) return;
    int pos = atomicAdd(&binpos[counts[r]], 1);
    perm[pos] = r;
}

// Kernel 2 (templated D): TWO relations per wave in COUNT-SORTED order.
template <int DD>
__global__ __launch_bounds__(256) void relation_kernel2_sorted_t(
        const float* __restrict__ relation_emb,
        const unsigned char* __restrict__ ctf8,
        const unsigned char* __restrict__ sf8,
        const float* __restrict__ W,
        const int* __restrict__ counts,
        const int* __restrict__ rel_start_idx,
        const int* __restrict__ perm,
        float2* __restrict__ lt,
        int R, float inv_ct_scale) {
    int w = blockIdx.x * (blockDim.x >> 6) + (threadIdx.x >> 6);
    int lane = threadIdx.x & 63;
    int p0 = w << 1;
    if (p0 >= R) return;
    bool has2 = (p0 + 1 < R);

    int r0 = perm[p0];
    int r1 = has2 ? perm[p0 + 1] : r0;

    int cnt0 = counts[r0];
    int st0  = rel_start_idx[r0];
    int cnt1 = counts[r1];
    int st1  = rel_start_idx[r1];

    const float* re0 = relation_emb + (size_t)r0 * DD;
    const float* re1 = relation_emb + (size_t)r1 * DD;
    const unsigned int* ct0 = (const unsigned int*)(ctf8 + (size_t)cnt0 * DD);
    const unsigned int* ct1 = (const unsigned int*)(ctf8 + (size_t)cnt1 * DD);
    const unsigned int* se0 = (const unsigned int*)(sf8 + (size_t)st0 * DD);
    const unsigned int* se1 = (const unsigned int*)(sf8 + (size_t)st1 * DD);
    const float* w2 = W + 2 * (size_t)DD;

    float lg0 = 0.f, tt0 = 0.f, lg1 = 0.f, tt1 = 0.f;
    #pragma unroll
    for (int idx = 0; idx < DD; idx += WAVE * 4) {
        int e4 = idx + lane * 4;
        int e1 = (idx >> 2) + lane;
        float4 rv0 = *(const float4*)(re0 + e4);
        float4 rv1 = *(const float4*)(re1 + e4);
        float4 wv  = *(const float4*)(w2 + e4);
        unsigned int cu0 = ct0[e1], su0 = se0[e1];
        unsigned int cu1 = ct1[e1], su1 = se1[e1];
        {
            float c0,c1,c2,c3, s0,s1,s2,s3;
            decode4_fp8(cu0, c0,c1,c2,c3);
            decode4_fp8(su0, s0,s1,s2,s3);
            float x0 = rv0.x*c0, x1 = rv0.y*c1, x2 = rv0.z*c2, x3 = rv0.w*c3;
            lg0 = fmaf(s0,x0, fmaf(s1,x1, fmaf(s2,x2, fmaf(s3,x3, lg0))));
            tt0 = fmaf(wv.x,x0, fmaf(wv.y,x1, fmaf(wv.z,x2, fmaf(wv.w,x3, tt0))));
        }
        {
            float c0,c1,c2,c3, s0,s1,s2,s3;
            decode4_fp8(cu1, c0,c1,c2,c3);
            decode4_fp8(su1, s0,s1,s2,s3);
            float x0 = rv1.x*c0, x1 = rv1.y*c1, x2 = rv1.z*c2, x3 = rv1.w*c3;
            lg1 = fmaf(s0,x0, fmaf(s1,x1, fmaf(s2,x2, fmaf(s3,x3, lg1))));
            tt1 = fmaf(wv.x,x0, fmaf(wv.y,x1, fmaf(wv.z,x2, fmaf(wv.w,x3, tt1))));
        }
    }
    lg0 = wave_reduce_sum(lg0) * inv_ct_scale;
    tt0 = wave_reduce_sum(tt0) * inv_ct_scale;
    lg1 = wave_reduce_sum(lg1) * inv_ct_scale;
    tt1 = wave_reduce_sum(tt1) * inv_ct_scale;
    if (lane == 0) {
        lt[r0] = make_float2(lg0, tt0);
        if (has2) lt[r1] = make_float2(lg1, tt1);
    }
}

// generic fallback (runtime D), one relation per wave, unsorted
__global__ void relation_kernel_gen(const float* __restrict__ relation_emb,
                                    const unsigned char* __restrict__ ctf8,
                                    const unsigned char* __restrict__ sf8,
                                    const float* __restrict__ W,
                                    const int* __restrict__ counts,
                                    const int* __restrict__ rel_start_idx,
                                    float2* __restrict__ lt,
                                    int R, int D, float inv_ct_scale) {
    int r = blockIdx.x * (blockDim.x >> 6) + (threadIdx.x >> 6);
    int lane = threadIdx.x & 63;
    if (r >= R) return;
    const float* re = relation_emb + (size_t)r * D;
    const unsigned int* ct = (const unsigned int*)(ctf8 + (size_t)counts[r] * D);
    const unsigned int* se = (const unsigned int*)(sf8 + (size_t)rel_start_idx[r] * D);
    const float* w2 = W + 2 * (size_t)D;
    float lg = 0.f, tt = 0.f;
    for (int idx = lane * 4; idx < D; idx += WAVE * 4) {
        float4 rv = *(const float4*)(re + idx);
        float4 wv = *(const float4*)(w2 + idx);
        float c0,c1,c2,c3, s0,s1,s2,s3;
        decode4_fp8(ct[idx >> 2], c0,c1,c2,c3);
        decode4_fp8(se[idx >> 2], s0,s1,s2,s3);
        float x0 = rv.x*c0, x1 = rv.y*c1, x2 = rv.z*c2, x3 = rv.w*c3;
        lg = fmaf(s0,x0, fmaf(s1,x1, fmaf(s2,x2, fmaf(s3,x3, lg))));
        tt = fmaf(wv.x,x0, fmaf(wv.y,x1, fmaf(wv.z,x2, fmaf(wv.w,x3, tt))));
    }
    lg = wave_reduce_sum(lg) * inv_ct_scale;
    tt = wave_reduce_sum(tt) * inv_ct_scale;
    if (lane == 0) lt[r] = make_float2(lg, tt);
}

// One thread per relation r: boundary where neighbor_idx changes.
__global__ void seg_mark_kernel(const int* __restrict__ neighbor_idx,
                                int* __restrict__ segs, int* __restrict__ sege, int R) {
    int r = blockIdx.x * blockDim.x + threadIdx.x;
    if (r >= R) return;
    int cur = neighbor_idx[r];
    if (r == 0) {
        segs[cur] = 0;
    } else {
        int prev = neighbor_idx[r - 1];
        if (prev != cur) {
            segs[cur] = r;
            sege[prev] = r;
        }
    }
    if (r == R - 1) sege[cur] = R;
}

// Kernel 3: per-segment softmax-weighted mean of t, bounds precomputed.
__global__ void segment_kernel(const float2* __restrict__ lt,
                               const int* __restrict__ segs,
                               const int* __restrict__ sege,
                               float* __restrict__ c,
                               int M) {
    int m = blockIdx.x * blockDim.x + threadIdx.x;
    if (m >= M) return;
    int s = segs[m], e = sege[m];
    if (e <= s) { c[m] = 0.f; return; }
    float mx = -INFINITY;
    for (int i = s; i < e; ++i) mx = fmaxf(mx, lt[i].x);
    float den = 0.f, num = 0.f;
    for (int i = s; i < e; ++i) {
        float2 v = lt[i];
        float ex = expf(v.x - mx);
        den += ex;
        num = fmaf(ex, v.y, num);
    }
    c[m] = num / den;
}

// Kernel 4: per-neighbor  score[m] = ew[start_idx[m]] + c[m] + <neighbor_emb[m], W3> + b
__global__ void score_kernel(const float* __restrict__ neighbor_emb,
                             const float* __restrict__ W,
                             const float* __restrict__ bptr,
                             const int* __restrict__ start_idx,
                             const float* __restrict__ ew,
                             const float* __restrict__ c,
                             float* __restrict__ out,
                             int M, int D) {
    int wavesPerBlock = blockDim.x >> 6;
    int m = blockIdx.x * wavesPerBlock + (threadIdx.x >> 6);
    int lane = threadIdx.x & 63;
    if (m >= M) return;
    const float* nb = neighbor_emb + (size_t)m * D;
    const float* w3 = W + 3 * (size_t)D;
    float acc = 0.f;
    for (int idx = lane * 4; idx < D; idx += WAVE * 4) {
        float4 nv = *(const float4*)(nb + idx);
        float4 wv = *(const float4*)(w3 + idx);
        acc = fmaf(nv.x, wv.x, acc);
        acc = fmaf(nv.y, wv.y, acc);
        acc = fmaf(nv.z, wv.z, acc);
        acc = fmaf(nv.w, wv.w, acc);
    }
    acc = wave_reduce_sum(acc);
    if (lane == 0) {
        out[m] = acc + ew[start_idx[m]] + c[m] + bptr[0];
    }
}

extern "C" void kernel_launch(void* const* d_in, const int* in_sizes, int n_in,
                              void* d_out, int out_size, void* d_ws, size_t ws_size,
                              hipStream_t stream) {
    const float* start_emb    = (const float*)d_in[0];
    const float* prompt_emb   = (const float*)d_in[1];
    const float* relation_emb = (const float*)d_in[2];
    const float* neighbor_emb = (const float*)d_in[3];
    const float* count_table  = (const float*)d_in[4];
    const float* W            = (const float*)d_in[5];
    const float* b            = (const float*)d_in[6];
    const int*   counts        = (const int*)d_in[7];
    const int*   rel_start_idx = (const int*)d_in[8];
    const int*   neighbor_idx  = (const int*)d_in[9];
    const int*   start_idx     = (const int*)d_in[10];

    int D = in_sizes[5] / 4;           // W is (1, 4D)
    int N = in_sizes[0] / D;
    int R = in_sizes[7];
    int M = in_sizes[10];
    int VOCAB = in_sizes[4] / D;

    const float CT_SCALE = 64.0f;

    char* ws = (char*)d_ws;
    size_t off = 0;
    float*  ew   = (float*)(ws + off);  off += ((size_t)N * 4 + 255) & ~(size_t)255;
    float2* lt   = (float2*)(ws + off); off += ((size_t)R * 8 + 255) & ~(size_t)255;
    float*  c    = (float*)(ws + off);  off += ((size_t)M * 4 + 255) & ~(size_t)255;
    int*    segs = (int*)(ws + off);    off += ((size_t)M * 4 + 255) & ~(size_t)255;
    int*    sege = (int*)(ws + off);    off += ((size_t)M * 4 + 255) & ~(size_t)255;
    int*    hist = (int*)(ws + off);    off += ((size_t)VOCAB * 4 + 255) & ~(size_t)255;
    int*    binpos = (int*)(ws + off);  off += ((size_t)VOCAB * 4 + 255) & ~(size_t)255;
    int*    perm = (int*)(ws + off);    off += ((size_t)R * 4 + 255) & ~(size_t)255;
    unsigned char* ctf8 = (unsigned char*)(ws + off); off += ((size_t)VOCAB * D + 255) & ~(size_t)255;
    unsigned char* sf8  = (unsigned char*)(ws + off); off += ((size_t)N * D + 255) & ~(size_t)255;
    float*  out  = (float*)d_out;

    // Prep: fp8 copies of the gathered tables
    {
        int n4 = (VOCAB * D) / 4;
        cvt_fp8_kernel<<<(n4 + 255) / 256, 256, 0, stream>>>(count_table,
                                                             (unsigned int*)ctf8, n4, CT_SCALE);
        int m4 = (N * D) / 4;
        cvt_fp8_kernel<<<(m4 + 255) / 256, 256, 0, stream>>>(start_emb,
                                                             (unsigned int*)sf8, m4, 1.0f);
    }
    // init segs/sege/hist; mark segment bounds; counting-sort by counts
    {
        int mx = M > VOCAB ? M : VOCAB;
        init_kernel<<<(mx + 255) / 256, 256, 0, stream>>>(segs, sege, hist, M, VOCAB);
        seg_mark_kernel<<<(R + 255) / 256, 256, 0, stream>>>(neighbor_idx, segs, sege, R);
        hist_kernel<<<(R + 255) / 256, 256, 0, stream>>>(counts, hist, R);
        scan_kernel<<<1, 1024, 0, stream>>>(hist, binpos, VOCAB);
        scatter_kernel<<<(R + 255) / 256, 256, 0, stream>>>(counts, binpos, perm, R);
    }
    // Kernel 1: entity dots (N waves)
    {
        int grid = (N + 3) / 4;
        entity_dots_kernel<<<grid, 256, 0, stream>>>(start_emb, prompt_emb, W, ew, N, D);
    }
    // Kernel 2: per-relation dots — 2 relations per wave, count-sorted order
    {
        if (D == 768) {
            int nw = (R + 1) / 2;
            int grid = (nw + 3) / 4;
            relation_kernel2_sorted_t<768><<<grid, 256, 0, stream>>>(
                relation_emb, ctf8, sf8, W, counts, rel_start_idx, perm, lt, R, 1.0f / CT_SCALE);
        } else {
            int grid = (R + 3) / 4;
            relation_kernel_gen<<<grid, 256, 0, stream>>>(
                relation_emb, ctf8, sf8, W, counts, rel_start_idx, lt, R, D, 1.0f / CT_SCALE);
        }
    }
    // Kernel 3: segment softmax-weighted mean (M threads, precomputed bounds)
    {
        int grid = (M + 255) / 256;
        segment_kernel<<<grid, 256, 0, stream>>>(lt, segs, sege, c, M);
    }
    // Kernel 4: final scores (M waves)
    {
        int grid = (M + 3) / 4;
        score_kernel<<<grid, 256, 0, stream>>>(neighbor_emb, W, b, start_idx, ew, c, out, M, D);
    }
}

// Round 11
// 358.460 us; speedup vs baseline: 1.3369x; 1.3369x over previous
//
#include <hip/hip_runtime.h>
#include <math.h>

#define WAVE 64

__device__ inline float wave_reduce_sum(float v) {
    #pragma unroll
    for (int off = 32; off > 0; off >>= 1)
        v += __shfl_xor(v, off, WAVE);
    return v;
}
__device__ inline float wave_reduce_max(float v) {
    #pragma unroll
    for (int off = 32; off > 0; off >>= 1)
        v = fmaxf(v, __shfl_xor(v, off, WAVE));
    return v;
}

// ---------- fp8 e4m3fn helpers ----------
__device__ inline unsigned int f32_to_e4m3(float a) {
    unsigned int u = __float_as_uint(a);
    unsigned int sgn = (u >> 31) << 7;
    unsigned int absu = u & 0x7FFFFFFFu;
    if (absu < 0x3C800000u) return sgn;            // |a| < 2^-6 -> signed zero
    int exp = (int)(absu >> 23) - 127;
    unsigned int m = absu & 0x7FFFFFu;
    unsigned int keep = m >> 20;
    unsigned int rest = m & 0xFFFFFu;
    if (rest > 0x80000u || (rest == 0x80000u && (keep & 1u))) keep++;
    if (keep == 8u) { keep = 0u; exp += 1; }
    if (exp > 8) { exp = 8; keep = 7u; }           // clamp (safety)
    return sgn | ((unsigned int)(exp + 7) << 3) | keep;
}

__device__ inline float e4m3_to_f32(unsigned int b) {
    unsigned int expm = b & 0x7Fu;
    unsigned int f = ((b & 0x80u) << 24) | ((expm + (120u << 3)) << 20);
    float v = __uint_as_float(f);
    return (expm & 0x78u) ? v : 0.0f;
}

__device__ inline void decode4_fp8(unsigned int u, float& a, float& b, float& c, float& d) {
#if __has_builtin(__builtin_amdgcn_cvt_pk_f32_fp8)
    auto lo = __builtin_amdgcn_cvt_pk_f32_fp8(u, false);
    auto hi = __builtin_amdgcn_cvt_pk_f32_fp8(u, true);
    a = lo[0]; b = lo[1]; c = hi[0]; d = hi[1];
#else
    a = e4m3_to_f32(u & 0xFFu);
    b = e4m3_to_f32((u >> 8) & 0xFFu);
    c = e4m3_to_f32((u >> 16) & 0xFFu);
    d = e4m3_to_f32((u >> 24) & 0xFFu);
#endif
}

// Convert f32 array to packed fp8 with pre-scale. n4 = n/4 uints out.
__global__ void cvt_fp8_kernel(const float* __restrict__ in,
                               unsigned int* __restrict__ out,
                               int n4, float scale) {
    int i = blockIdx.x * blockDim.x + threadIdx.x;
    if (i >= n4) return;
    float4 v = ((const float4*)in)[i];
    unsigned int b0 = f32_to_e4m3(v.x * scale);
    unsigned int b1 = f32_to_e4m3(v.y * scale);
    unsigned int b2 = f32_to_e4m3(v.z * scale);
    unsigned int b3 = f32_to_e4m3(v.w * scale);
    out[i] = b0 | (b1 << 8) | (b2 << 16) | (b3 << 24);
}

// Kernel 1: per-entity  ew[i] = dot(start_emb[i], W0) + dot(prompt_emb[i], W1)
__global__ void entity_dots_kernel(const float* __restrict__ start_emb,
                                   const float* __restrict__ prompt_emb,
                                   const float* __restrict__ W,
                                   float* __restrict__ ew, int N, int D) {
    int wavesPerBlock = blockDim.x >> 6;
    int i = blockIdx.x * wavesPerBlock + (threadIdx.x >> 6);
    int lane = threadIdx.x & 63;
    if (i >= N) return;
    const float* s  = start_emb  + (size_t)i * D;
    const float* p  = prompt_emb + (size_t)i * D;
    const float* w0 = W;
    const float* w1 = W + D;
    float acc = 0.f;
    for (int idx = lane * 4; idx < D; idx += WAVE * 4) {
        float4 sv  = *(const float4*)(s  + idx);
        float4 pv  = *(const float4*)(p  + idx);
        float4 w0v = *(const float4*)(w0 + idx);
        float4 w1v = *(const float4*)(w1 + idx);
        acc = fmaf(sv.x, w0v.x, acc);
        acc = fmaf(sv.y, w0v.y, acc);
        acc = fmaf(sv.z, w0v.z, acc);
        acc = fmaf(sv.w, w0v.w, acc);
        acc = fmaf(pv.x, w1v.x, acc);
        acc = fmaf(pv.y, w1v.y, acc);
        acc = fmaf(pv.z, w1v.z, acc);
        acc = fmaf(pv.w, w1v.w, acc);
    }
    acc = wave_reduce_sum(acc);
    if (lane == 0) ew[i] = acc;
}

// Kernel 2 (templated D): TWO adjacent relations per wave, loop form, NATURAL order.
template <int DD>
__global__ __launch_bounds__(256) void relation_kernel2_t(
        const float* __restrict__ relation_emb,
        const unsigned char* __restrict__ ctf8,
        const unsigned char* __restrict__ sf8,
        const float* __restrict__ W,
        const int* __restrict__ counts,
        const int* __restrict__ rel_start_idx,
        float2* __restrict__ lt,
        int R, float inv_ct_scale) {
    int w = blockIdx.x * (blockDim.x >> 6) + (threadIdx.x >> 6);
    int lane = threadIdx.x & 63;
    int r0 = w << 1;
    if (r0 >= R) return;
    bool has2 = (r0 + 1 < R);

    int cnt0 = counts[r0];
    int st0  = rel_start_idx[r0];
    int cnt1 = has2 ? counts[r0 + 1] : cnt0;
    int st1  = has2 ? rel_start_idx[r0 + 1] : st0;

    const float* re0 = relation_emb + (size_t)r0 * DD;
    const float* re1 = re0 + (has2 ? DD : 0);
    const unsigned int* ct0 = (const unsigned int*)(ctf8 + (size_t)cnt0 * DD);
    const unsigned int* ct1 = (const unsigned int*)(ctf8 + (size_t)cnt1 * DD);
    const unsigned int* se0 = (const unsigned int*)(sf8 + (size_t)st0 * DD);
    const unsigned int* se1 = (const unsigned int*)(sf8 + (size_t)st1 * DD);
    const float* w2 = W + 2 * (size_t)DD;

    float lg0 = 0.f, tt0 = 0.f, lg1 = 0.f, tt1 = 0.f;
    #pragma unroll
    for (int idx = 0; idx < DD; idx += WAVE * 4) {
        int e4 = idx + lane * 4;
        int e1 = (idx >> 2) + lane;
        float4 rv0 = *(const float4*)(re0 + e4);
        float4 rv1 = *(const float4*)(re1 + e4);
        float4 wv  = *(const float4*)(w2 + e4);
        unsigned int cu0 = ct0[e1], su0 = se0[e1];
        unsigned int cu1 = ct1[e1], su1 = se1[e1];
        {
            float c0,c1,c2,c3, s0,s1,s2,s3;
            decode4_fp8(cu0, c0,c1,c2,c3);
            decode4_fp8(su0, s0,s1,s2,s3);
            float x0 = rv0.x*c0, x1 = rv0.y*c1, x2 = rv0.z*c2, x3 = rv0.w*c3;
            lg0 = fmaf(s0,x0, fmaf(s1,x1, fmaf(s2,x2, fmaf(s3,x3, lg0))));
            tt0 = fmaf(wv.x,x0, fmaf(wv.y,x1, fmaf(wv.z,x2, fmaf(wv.w,x3, tt0))));
        }
        {
            float c0,c1,c2,c3, s0,s1,s2,s3;
            decode4_fp8(cu1, c0,c1,c2,c3);
            decode4_fp8(su1, s0,s1,s2,s3);
            float x0 = rv1.x*c0, x1 = rv1.y*c1, x2 = rv1.z*c2, x3 = rv1.w*c3;
            lg1 = fmaf(s0,x0, fmaf(s1,x1, fmaf(s2,x2, fmaf(s3,x3, lg1))));
            tt1 = fmaf(wv.x,x0, fmaf(wv.y,x1, fmaf(wv.z,x2, fmaf(wv.w,x3, tt1))));
        }
    }
    lg0 = wave_reduce_sum(lg0) * inv_ct_scale;
    tt0 = wave_reduce_sum(tt0) * inv_ct_scale;
    lg1 = wave_reduce_sum(lg1) * inv_ct_scale;
    tt1 = wave_reduce_sum(tt1) * inv_ct_scale;
    if (lane == 0) {
        if (has2) {
            float4 v; v.x = lg0; v.y = tt0; v.z = lg1; v.w = tt1;
            *(float4*)(lt + r0) = v;                 // r0 even -> 16B aligned
        } else {
            lt[r0] = make_float2(lg0, tt0);
        }
    }
}

// generic fallback (runtime D), one relation per wave
__global__ void relation_kernel_gen(const float* __restrict__ relation_emb,
                                    const unsigned char* __restrict__ ctf8,
                                    const unsigned char* __restrict__ sf8,
                                    const float* __restrict__ W,
                                    const int* __restrict__ counts,
                                    const int* __restrict__ rel_start_idx,
                                    float2* __restrict__ lt,
                                    int R, int D, float inv_ct_scale) {
    int r = blockIdx.x * (blockDim.x >> 6) + (threadIdx.x >> 6);
    int lane = threadIdx.x & 63;
    if (r >= R) return;
    const float* re = relation_emb + (size_t)r * D;
    const unsigned int* ct = (const unsigned int*)(ctf8 + (size_t)counts[r] * D);
    const unsigned int* se = (const unsigned int*)(sf8 + (size_t)rel_start_idx[r] * D);
    const float* w2 = W + 2 * (size_t)D;
    float lg = 0.f, tt = 0.f;
    for (int idx = lane * 4; idx < D; idx += WAVE * 4) {
        float4 rv = *(const float4*)(re + idx);
        float4 wv = *(const float4*)(w2 + idx);
        float c0,c1,c2,c3, s0,s1,s2,s3;
        decode4_fp8(ct[idx >> 2], c0,c1,c2,c3);
        decode4_fp8(se[idx >> 2], s0,s1,s2,s3);
        float x0 = rv.x*c0, x1 = rv.y*c1, x2 = rv.z*c2, x3 = rv.w*c3;
        lg = fmaf(s0,x0, fmaf(s1,x1, fmaf(s2,x2, fmaf(s3,x3, lg))));
        tt = fmaf(wv.x,x0, fmaf(wv.y,x1, fmaf(wv.z,x2, fmaf(wv.w,x3, tt))));
    }
    lg = wave_reduce_sum(lg) * inv_ct_scale;
    tt = wave_reduce_sum(tt) * inv_ct_scale;
    if (lane == 0) lt[r] = make_float2(lg, tt);
}

// ---------- Segment bounds precompute ----------
__global__ void seg_init_kernel(int* __restrict__ segs, int* __restrict__ sege, int M) {
    int m = blockIdx.x * blockDim.x + threadIdx.x;
    if (m < M) { segs[m] = 0; sege[m] = 0; }
}

__global__ void seg_mark_kernel(const int* __restrict__ neighbor_idx,
                                int* __restrict__ segs, int* __restrict__ sege, int R) {
    int r = blockIdx.x * blockDim.x + threadIdx.x;
    if (r >= R) return;
    int cur = neighbor_idx[r];
    if (r == 0) {
        segs[cur] = 0;
    } else {
        int prev = neighbor_idx[r - 1];
        if (prev != cur) {
            segs[cur] = r;
            sege[prev] = r;
        }
    }
    if (r == R - 1) sege[cur] = R;
}

// Kernel 3+4 fused: one wave per neighbor m.
// cval = segment softmax-weighted mean of t over [segs[m], sege[m])  (lane-parallel)
// score[m] = ew[start_idx[m]] + cval + <neighbor_emb[m], W3> + b
template <int DD>
__global__ __launch_bounds__(256) void score_fused_t(
        const float* __restrict__ neighbor_emb,
        const float* __restrict__ W,
        const float* __restrict__ bptr,
        const int* __restrict__ start_idx,
        const float* __restrict__ ew,
        const float2* __restrict__ lt,
        const int* __restrict__ segs,
        const int* __restrict__ sege,
        float* __restrict__ out,
        int M) {
    int m = blockIdx.x * (blockDim.x >> 6) + (threadIdx.x >> 6);
    int lane = threadIdx.x & 63;
    if (m >= M) return;

    const float* nb = neighbor_emb + (size_t)m * DD;
    const float* w3 = W + 3 * (size_t)DD;

    float acc = 0.f;
    #pragma unroll
    for (int idx = 0; idx < DD; idx += WAVE * 4) {
        float4 nv = *(const float4*)(nb + idx + lane * 4);
        float4 wv = *(const float4*)(w3 + idx + lane * 4);
        acc = fmaf(nv.x, wv.x, acc);
        acc = fmaf(nv.y, wv.y, acc);
        acc = fmaf(nv.z, wv.z, acc);
        acc = fmaf(nv.w, wv.w, acc);
    }

    int s = segs[m], e = sege[m];
    float cval = 0.f;
    if (e > s) {
        float mx = -INFINITY;
        for (int i = s + lane; i < e; i += WAVE) mx = fmaxf(mx, lt[i].x);
        mx = wave_reduce_max(mx);
        float den = 0.f, num = 0.f;
        for (int i = s + lane; i < e; i += WAVE) {
            float2 v = lt[i];
            float exv = expf(v.x - mx);
            den += exv;
            num = fmaf(exv, v.y, num);
        }
        den = wave_reduce_sum(den);
        num = wave_reduce_sum(num);
        cval = num / den;
    }

    acc = wave_reduce_sum(acc);
    if (lane == 0) out[m] = acc + ew[start_idx[m]] + cval + bptr[0];
}

// generic fallback (runtime D)
__global__ void score_fused_gen(const float* __restrict__ neighbor_emb,
                                const float* __restrict__ W,
                                const float* __restrict__ bptr,
                                const int* __restrict__ start_idx,
                                const float* __restrict__ ew,
                                const float2* __restrict__ lt,
                                const int* __restrict__ segs,
                                const int* __restrict__ sege,
                                float* __restrict__ out,
                                int M, int D) {
    int m = blockIdx.x * (blockDim.x >> 6) + (threadIdx.x >> 6);
    int lane = threadIdx.x & 63;
    if (m >= M) return;
    const float* nb = neighbor_emb + (size_t)m * D;
    const float* w3 = W + 3 * (size_t)D;
    float acc = 0.f;
    for (int idx = lane * 4; idx < D; idx += WAVE * 4) {
        float4 nv = *(const float4*)(nb + idx);
        float4 wv = *(const float4*)(w3 + idx);
        acc = fmaf(nv.x, wv.x, acc);
        acc = fmaf(nv.y, wv.y, acc);
        acc = fmaf(nv.z, wv.z, acc);
        acc = fmaf(nv.w, wv.w, acc);
    }
    int s = segs[m], e = sege[m];
    float cval = 0.f;
    if (e > s) {
        float mx = -INFINITY;
        for (int i = s + lane; i < e; i += WAVE) mx = fmaxf(mx, lt[i].x);
        mx = wave_reduce_max(mx);
        float den = 0.f, num = 0.f;
        for (int i = s + lane; i < e; i += WAVE) {
            float2 v = lt[i];
            float exv = expf(v.x - mx);
            den += exv;
            num = fmaf(exv, v.y, num);
        }
        den = wave_reduce_sum(den);
        num = wave_reduce_sum(num);
        cval = num / den;
    }
    acc = wave_reduce_sum(acc);
    if (lane == 0) out[m] = acc + ew[start_idx[m]] + cval + bptr[0];
}

extern "C" void kernel_launch(void* const* d_in, const int* in_sizes, int n_in,
                              void* d_out, int out_size, void* d_ws, size_t ws_size,
                              hipStream_t stream) {
    const float* start_emb    = (const float*)d_in[0];
    const float* prompt_emb   = (const float*)d_in[1];
    const float* relation_emb = (const float*)d_in[2];
    const float* neighbor_emb = (const float*)d_in[3];
    const float* count_table  = (const float*)d_in[4];
    const float* W            = (const float*)d_in[5];
    const float* b            = (const float*)d_in[6];
    const int*   counts        = (const int*)d_in[7];
    const int*   rel_start_idx = (const int*)d_in[8];
    const int*   neighbor_idx  = (const int*)d_in[9];
    const int*   start_idx     = (const int*)d_in[10];

    int D = in_sizes[5] / 4;           // W is (1, 4D)
    int N = in_sizes[0] / D;
    int R = in_sizes[7];
    int M = in_sizes[10];
    int VOCAB = in_sizes[4] / D;

    const float CT_SCALE = 64.0f;

    char* ws = (char*)d_ws;
    size_t off = 0;
    float*  ew   = (float*)(ws + off);  off += ((size_t)N * 4 + 255) & ~(size_t)255;
    float2* lt   = (float2*)(ws + off); off += ((size_t)R * 8 + 255) & ~(size_t)255;
    int*    segs = (int*)(ws + off);    off += ((size_t)M * 4 + 255) & ~(size_t)255;
    int*    sege = (int*)(ws + off);    off += ((size_t)M * 4 + 255) & ~(size_t)255;
    unsigned char* ctf8 = (unsigned char*)(ws + off); off += ((size_t)VOCAB * D + 255) & ~(size_t)255;
    unsigned char* sf8  = (unsigned char*)(ws + off); off += ((size_t)N * D + 255) & ~(size_t)255;
    float*  out  = (float*)d_out;

    // Prep: fp8 copies of the gathered tables
    {
        int n4 = (VOCAB * D) / 4;
        cvt_fp8_kernel<<<(n4 + 255) / 256, 256, 0, stream>>>(count_table,
                                                             (unsigned int*)ctf8, n4, CT_SCALE);
        int m4 = (N * D) / 4;
        cvt_fp8_kernel<<<(m4 + 255) / 256, 256, 0, stream>>>(start_emb,
                                                             (unsigned int*)sf8, m4, 1.0f);
    }
    // Segment bounds: init + mark
    seg_init_kernel<<<(M + 255) / 256, 256, 0, stream>>>(segs, sege, M);
    seg_mark_kernel<<<(R + 255) / 256, 256, 0, stream>>>(neighbor_idx, segs, sege, R);

    // Kernel 1: entity dots (N waves)
    {
        int grid = (N + 3) / 4;
        entity_dots_kernel<<<grid, 256, 0, stream>>>(start_emb, prompt_emb, W, ew, N, D);
    }
    // Kernel 2: per-relation dots — 2 adjacent relations per wave, natural order
    {
        if (D == 768) {
            int nw = (R + 1) / 2;
            int grid = (nw + 3) / 4;
            relation_kernel2_t<768><<<grid, 256, 0, stream>>>(
                relation_emb, ctf8, sf8, W, counts, rel_start_idx, lt, R, 1.0f / CT_SCALE);
        } else {
            int grid = (R + 3) / 4;
            relation_kernel_gen<<<grid, 256, 0, stream>>>(
                relation_emb, ctf8, sf8, W, counts, rel_start_idx, lt, R, D, 1.0f / CT_SCALE);
        }
    }
    // Kernel 3+4 fused: segment softmax + final score (M waves)
    {
        int grid = (M + 3) / 4;
        if (D == 768) {
            score_fused_t<768><<<grid, 256, 0, stream>>>(
                neighbor_emb, W, b, start_idx, ew, lt, segs, sege, out, M);
        } else {
            score_fused_gen<<<grid, 256, 0, stream>>>(
                neighbor_emb, W, b, start_idx, ew, lt, segs, sege, out, M, D);
        }
    }
}

// Round 12
// 332.434 us; speedup vs baseline: 1.4416x; 1.0783x over previous
//
#include <hip/hip_runtime.h>
#include <math.h>

#define WAVE 64

typedef float f32x4 __attribute__((ext_vector_type(4)));

__device__ inline float wave_reduce_sum(float v) {
    #pragma unroll
    for (int off = 32; off > 0; off >>= 1)
        v += __shfl_xor(v, off, WAVE);
    return v;
}
__device__ inline float wave_reduce_max(float v) {
    #pragma unroll
    for (int off = 32; off > 0; off >>= 1)
        v = fmaxf(v, __shfl_xor(v, off, WAVE));
    return v;
}

// ---------- fp8 e4m3fn helpers ----------
__device__ inline unsigned int f32_to_e4m3(float a) {
    unsigned int u = __float_as_uint(a);
    unsigned int sgn = (u >> 31) << 7;
    unsigned int absu = u & 0x7FFFFFFFu;
    if (absu < 0x3C800000u) return sgn;            // |a| < 2^-6 -> signed zero
    int exp = (int)(absu >> 23) - 127;
    unsigned int m = absu & 0x7FFFFFu;
    unsigned int keep = m >> 20;
    unsigned int rest = m & 0xFFFFFu;
    if (rest > 0x80000u || (rest == 0x80000u && (keep & 1u))) keep++;
    if (keep == 8u) { keep = 0u; exp += 1; }
    if (exp > 8) { exp = 8; keep = 7u; }           // clamp (safety)
    return sgn | ((unsigned int)(exp + 7) << 3) | keep;
}

__device__ inline float e4m3_to_f32(unsigned int b) {
    unsigned int expm = b & 0x7Fu;
    unsigned int f = ((b & 0x80u) << 24) | ((expm + (120u << 3)) << 20);
    float v = __uint_as_float(f);
    return (expm & 0x78u) ? v : 0.0f;
}

__device__ inline void decode4_fp8(unsigned int u, float& a, float& b, float& c, float& d) {
#if __has_builtin(__builtin_amdgcn_cvt_pk_f32_fp8)
    auto lo = __builtin_amdgcn_cvt_pk_f32_fp8(u, false);
    auto hi = __builtin_amdgcn_cvt_pk_f32_fp8(u, true);
    a = lo[0]; b = lo[1]; c = hi[0]; d = hi[1];
#else
    a = e4m3_to_f32(u & 0xFFu);
    b = e4m3_to_f32((u >> 8) & 0xFFu);
    c = e4m3_to_f32((u >> 16) & 0xFFu);
    d = e4m3_to_f32((u >> 24) & 0xFFu);
#endif
}

// Convert f32 array to packed fp8 with pre-scale. n4 = n/4 uints out.
__global__ void cvt_fp8_kernel(const float* __restrict__ in,
                               unsigned int* __restrict__ out,
                               int n4, float scale) {
    int i = blockIdx.x * blockDim.x + threadIdx.x;
    if (i >= n4) return;
    float4 v = ((const float4*)in)[i];
    unsigned int b0 = f32_to_e4m3(v.x * scale);
    unsigned int b1 = f32_to_e4m3(v.y * scale);
    unsigned int b2 = f32_to_e4m3(v.z * scale);
    unsigned int b3 = f32_to_e4m3(v.w * scale);
    out[i] = b0 | (b1 << 8) | (b2 << 16) | (b3 << 24);
}

// Kernel 1: per-entity  ew[i] = dot(start_emb[i], W0) + dot(prompt_emb[i], W1)
__global__ void entity_dots_kernel(const float* __restrict__ start_emb,
                                   const float* __restrict__ prompt_emb,
                                   const float* __restrict__ W,
                                   float* __restrict__ ew, int N, int D) {
    int wavesPerBlock = blockDim.x >> 6;
    int i = blockIdx.x * wavesPerBlock + (threadIdx.x >> 6);
    int lane = threadIdx.x & 63;
    if (i >= N) return;
    const float* s  = start_emb  + (size_t)i * D;
    const float* p  = prompt_emb + (size_t)i * D;
    const float* w0 = W;
    const float* w1 = W + D;
    float acc = 0.f;
    for (int idx = lane * 4; idx < D; idx += WAVE * 4) {
        float4 sv  = *(const float4*)(s  + idx);
        float4 pv  = *(const float4*)(p  + idx);
        float4 w0v = *(const float4*)(w0 + idx);
        float4 w1v = *(const float4*)(w1 + idx);
        acc = fmaf(sv.x, w0v.x, acc);
        acc = fmaf(sv.y, w0v.y, acc);
        acc = fmaf(sv.z, w0v.z, acc);
        acc = fmaf(sv.w, w0v.w, acc);
        acc = fmaf(pv.x, w1v.x, acc);
        acc = fmaf(pv.y, w1v.y, acc);
        acc = fmaf(pv.z, w1v.z, acc);
        acc = fmaf(pv.w, w1v.w, acc);
    }
    acc = wave_reduce_sum(acc);
    if (lane == 0) ew[i] = acc;
}

// Kernel 2 (templated D): TWO adjacent relations per wave, loop form, NATURAL order.
// ONLY change vs R11: relation_emb stream loads are NONTEMPORAL (protect L2 for gathers).
template <int DD>
__global__ __launch_bounds__(256) void relation_kernel2_t(
        const float* __restrict__ relation_emb,
        const unsigned char* __restrict__ ctf8,
        const unsigned char* __restrict__ sf8,
        const float* __restrict__ W,
        const int* __restrict__ counts,
        const int* __restrict__ rel_start_idx,
        float2* __restrict__ lt,
        int R, float inv_ct_scale) {
    int w = blockIdx.x * (blockDim.x >> 6) + (threadIdx.x >> 6);
    int lane = threadIdx.x & 63;
    int r0 = w << 1;
    if (r0 >= R) return;
    bool has2 = (r0 + 1 < R);

    int cnt0 = counts[r0];
    int st0  = rel_start_idx[r0];
    int cnt1 = has2 ? counts[r0 + 1] : cnt0;
    int st1  = has2 ? rel_start_idx[r0 + 1] : st0;

    const float* re0 = relation_emb + (size_t)r0 * DD;
    const float* re1 = re0 + (has2 ? DD : 0);
    const unsigned int* ct0 = (const unsigned int*)(ctf8 + (size_t)cnt0 * DD);
    const unsigned int* ct1 = (const unsigned int*)(ctf8 + (size_t)cnt1 * DD);
    const unsigned int* se0 = (const unsigned int*)(sf8 + (size_t)st0 * DD);
    const unsigned int* se1 = (const unsigned int*)(sf8 + (size_t)st1 * DD);
    const float* w2 = W + 2 * (size_t)DD;

    float lg0 = 0.f, tt0 = 0.f, lg1 = 0.f, tt1 = 0.f;
    #pragma unroll
    for (int idx = 0; idx < DD; idx += WAVE * 4) {
        int e4 = idx + lane * 4;
        int e1 = (idx >> 2) + lane;
        f32x4 rv0 = __builtin_nontemporal_load((const f32x4*)(re0 + e4));
        f32x4 rv1 = __builtin_nontemporal_load((const f32x4*)(re1 + e4));
        float4 wv  = *(const float4*)(w2 + e4);
        unsigned int cu0 = ct0[e1], su0 = se0[e1];
        unsigned int cu1 = ct1[e1], su1 = se1[e1];
        {
            float c0,c1,c2,c3, s0,s1,s2,s3;
            decode4_fp8(cu0, c0,c1,c2,c3);
            decode4_fp8(su0, s0,s1,s2,s3);
            float x0 = rv0.x*c0, x1 = rv0.y*c1, x2 = rv0.z*c2, x3 = rv0.w*c3;
            lg0 = fmaf(s0,x0, fmaf(s1,x1, fmaf(s2,x2, fmaf(s3,x3, lg0))));
            tt0 = fmaf(wv.x,x0, fmaf(wv.y,x1, fmaf(wv.z,x2, fmaf(wv.w,x3, tt0))));
        }
        {
            float c0,c1,c2,c3, s0,s1,s2,s3;
            decode4_fp8(cu1, c0,c1,c2,c3);
            decode4_fp8(su1, s0,s1,s2,s3);
            float x0 = rv1.x*c0, x1 = rv1.y*c1, x2 = rv1.z*c2, x3 = rv1.w*c3;
            lg1 = fmaf(s0,x0, fmaf(s1,x1, fmaf(s2,x2, fmaf(s3,x3, lg1))));
            tt1 = fmaf(wv.x,x0, fmaf(wv.y,x1, fmaf(wv.z,x2, fmaf(wv.w,x3, tt1))));
        }
    }
    lg0 = wave_reduce_sum(lg0) * inv_ct_scale;
    tt0 = wave_reduce_sum(tt0) * inv_ct_scale;
    lg1 = wave_reduce_sum(lg1) * inv_ct_scale;
    tt1 = wave_reduce_sum(tt1) * inv_ct_scale;
    if (lane == 0) {
        if (has2) {
            float4 v; v.x = lg0; v.y = tt0; v.z = lg1; v.w = tt1;
            *(float4*)(lt + r0) = v;                 // r0 even -> 16B aligned
        } else {
            lt[r0] = make_float2(lg0, tt0);
        }
    }
}

// generic fallback (runtime D), one relation per wave
__global__ void relation_kernel_gen(const float* __restrict__ relation_emb,
                                    const unsigned char* __restrict__ ctf8,
                                    const unsigned char* __restrict__ sf8,
                                    const float* __restrict__ W,
                                    const int* __restrict__ counts,
                                    const int* __restrict__ rel_start_idx,
                                    float2* __restrict__ lt,
                                    int R, int D, float inv_ct_scale) {
    int r = blockIdx.x * (blockDim.x >> 6) + (threadIdx.x >> 6);
    int lane = threadIdx.x & 63;
    if (r >= R) return;
    const float* re = relation_emb + (size_t)r * D;
    const unsigned int* ct = (const unsigned int*)(ctf8 + (size_t)counts[r] * D);
    const unsigned int* se = (const unsigned int*)(sf8 + (size_t)rel_start_idx[r] * D);
    const float* w2 = W + 2 * (size_t)D;
    float lg = 0.f, tt = 0.f;
    for (int idx = lane * 4; idx < D; idx += WAVE * 4) {
        float4 rv = *(const float4*)(re + idx);
        float4 wv = *(const float4*)(w2 + idx);
        float c0,c1,c2,c3, s0,s1,s2,s3;
        decode4_fp8(ct[idx >> 2], c0,c1,c2,c3);
        decode4_fp8(se[idx >> 2], s0,s1,s2,s3);
        float x0 = rv.x*c0, x1 = rv.y*c1, x2 = rv.z*c2, x3 = rv.w*c3;
        lg = fmaf(s0,x0, fmaf(s1,x1, fmaf(s2,x2, fmaf(s3,x3, lg))));
        tt = fmaf(wv.x,x0, fmaf(wv.y,x1, fmaf(wv.z,x2, fmaf(wv.w,x3, tt))));
    }
    lg = wave_reduce_sum(lg) * inv_ct_scale;
    tt = wave_reduce_sum(tt) * inv_ct_scale;
    if (lane == 0) lt[r] = make_float2(lg, tt);
}

// ---------- Segment bounds precompute ----------
__global__ void seg_init_kernel(int* __restrict__ segs, int* __restrict__ sege, int M) {
    int m = blockIdx.x * blockDim.x + threadIdx.x;
    if (m < M) { segs[m] = 0; sege[m] = 0; }
}

__global__ void seg_mark_kernel(const int* __restrict__ neighbor_idx,
                                int* __restrict__ segs, int* __restrict__ sege, int R) {
    int r = blockIdx.x * blockDim.x + threadIdx.x;
    if (r >= R) return;
    int cur = neighbor_idx[r];
    if (r == 0) {
        segs[cur] = 0;
    } else {
        int prev = neighbor_idx[r - 1];
        if (prev != cur) {
            segs[cur] = r;
            sege[prev] = r;
        }
    }
    if (r == R - 1) sege[cur] = R;
}

// Kernel 3+4 fused: one wave per neighbor m.
template <int DD>
__global__ __launch_bounds__(256) void score_fused_t(
        const float* __restrict__ neighbor_emb,
        const float* __restrict__ W,
        const float* __restrict__ bptr,
        const int* __restrict__ start_idx,
        const float* __restrict__ ew,
        const float2* __restrict__ lt,
        const int* __restrict__ segs,
        const int* __restrict__ sege,
        float* __restrict__ out,
        int M) {
    int m = blockIdx.x * (blockDim.x >> 6) + (threadIdx.x >> 6);
    int lane = threadIdx.x & 63;
    if (m >= M) return;

    const float* nb = neighbor_emb + (size_t)m * DD;
    const float* w3 = W + 3 * (size_t)DD;

    float acc = 0.f;
    #pragma unroll
    for (int idx = 0; idx < DD; idx += WAVE * 4) {
        float4 nv = *(const float4*)(nb + idx + lane * 4);
        float4 wv = *(const float4*)(w3 + idx + lane * 4);
        acc = fmaf(nv.x, wv.x, acc);
        acc = fmaf(nv.y, wv.y, acc);
        acc = fmaf(nv.z, wv.z, acc);
        acc = fmaf(nv.w, wv.w, acc);
    }

    int s = segs[m], e = sege[m];
    float cval = 0.f;
    if (e > s) {
        float mx = -INFINITY;
        for (int i = s + lane; i < e; i += WAVE) mx = fmaxf(mx, lt[i].x);
        mx = wave_reduce_max(mx);
        float den = 0.f, num = 0.f;
        for (int i = s + lane; i < e; i += WAVE) {
            float2 v = lt[i];
            float exv = expf(v.x - mx);
            den += exv;
            num = fmaf(exv, v.y, num);
        }
        den = wave_reduce_sum(den);
        num = wave_reduce_sum(num);
        cval = num / den;
    }

    acc = wave_reduce_sum(acc);
    if (lane == 0) out[m] = acc + ew[start_idx[m]] + cval + bptr[0];
}

// generic fallback (runtime D)
__global__ void score_fused_gen(const float* __restrict__ neighbor_emb,
                                const float* __restrict__ W,
                                const float* __restrict__ bptr,
                                const int* __restrict__ start_idx,
                                const float* __restrict__ ew,
                                const float2* __restrict__ lt,
                                const int* __restrict__ segs,
                                const int* __restrict__ sege,
                                float* __restrict__ out,
                                int M, int D) {
    int m = blockIdx.x * (blockDim.x >> 6) + (threadIdx.x >> 6);
    int lane = threadIdx.x & 63;
    if (m >= M) return;
    const float* nb = neighbor_emb + (size_t)m * D;
    const float* w3 = W + 3 * (size_t)D;
    float acc = 0.f;
    for (int idx = lane * 4; idx < D; idx += WAVE * 4) {
        float4 nv = *(const float4*)(nb + idx);
        float4 wv = *(const float4*)(w3 + idx);
        acc = fmaf(nv.x, wv.x, acc);
        acc = fmaf(nv.y, wv.y, acc);
        acc = fmaf(nv.z, wv.z, acc);
        acc = fmaf(nv.w, wv.w, acc);
    }
    int s = segs[m], e = sege[m];
    float cval = 0.f;
    if (e > s) {
        float mx = -INFINITY;
        for (int i = s + lane; i < e; i += WAVE) mx = fmaxf(mx, lt[i].x);
        mx = wave_reduce_max(mx);
        float den = 0.f, num = 0.f;
        for (int i = s + lane; i < e; i += WAVE) {
            float2 v = lt[i];
            float exv = expf(v.x - mx);
            den += exv;
            num = fmaf(exv, v.y, num);
        }
        den = wave_reduce_sum(den);
        num = wave_reduce_sum(num);
        cval = num / den;
    }
    acc = wave_reduce_sum(acc);
    if (lane == 0) out[m] = acc + ew[start_idx[m]] + cval + bptr[0];
}

extern "C" void kernel_launch(void* const* d_in, const int* in_sizes, int n_in,
                              void* d_out, int out_size, void* d_ws, size_t ws_size,
                              hipStream_t stream) {
    const float* start_emb    = (const float*)d_in[0];
    const float* prompt_emb   = (const float*)d_in[1];
    const float* relation_emb = (const float*)d_in[2];
    const float* neighbor_emb = (const float*)d_in[3];
    const float* count_table  = (const float*)d_in[4];
    const float* W            = (const float*)d_in[5];
    const float* b            = (const float*)d_in[6];
    const int*   counts        = (const int*)d_in[7];
    const int*   rel_start_idx = (const int*)d_in[8];
    const int*   neighbor_idx  = (const int*)d_in[9];
    const int*   start_idx     = (const int*)d_in[10];

    int D = in_sizes[5] / 4;           // W is (1, 4D)
    int N = in_sizes[0] / D;
    int R = in_sizes[7];
    int M = in_sizes[10];
    int VOCAB = in_sizes[4] / D;

    const float CT_SCALE = 64.0f;

    char* ws = (char*)d_ws;
    size_t off = 0;
    float*  ew   = (float*)(ws + off);  off += ((size_t)N * 4 + 255) & ~(size_t)255;
    float2* lt   = (float2*)(ws + off); off += ((size_t)R * 8 + 255) & ~(size_t)255;
    int*    segs = (int*)(ws + off);    off += ((size_t)M * 4 + 255) & ~(size_t)255;
    int*    sege = (int*)(ws + off);    off += ((size_t)M * 4 + 255) & ~(size_t)255;
    unsigned char* ctf8 = (unsigned char*)(ws + off); off += ((size_t)VOCAB * D + 255) & ~(size_t)255;
    unsigned char* sf8  = (unsigned char*)(ws + off); off += ((size_t)N * D + 255) & ~(size_t)255;
    float*  out  = (float*)d_out;

    // Prep: fp8 copies of the gathered tables
    {
        int n4 = (VOCAB * D) / 4;
        cvt_fp8_kernel<<<(n4 + 255) / 256, 256, 0, stream>>>(count_table,
                                                             (unsigned int*)ctf8, n4, CT_SCALE);
        int m4 = (N * D) / 4;
        cvt_fp8_kernel<<<(m4 + 255) / 256, 256, 0, stream>>>(start_emb,
                                                             (unsigned int*)sf8, m4, 1.0f);
    }
    // Segment bounds: init + mark
    seg_init_kernel<<<(M + 255) / 256, 256, 0, stream>>>(segs, sege, M);
    seg_mark_kernel<<<(R + 255) / 256, 256, 0, stream>>>(neighbor_idx, segs, sege, R);

    // Kernel 1: entity dots (N waves)
    {
        int grid = (N + 3) / 4;
        entity_dots_kernel<<<grid, 256, 0, stream>>>(start_emb, prompt_emb, W, ew, N, D);
    }
    // Kernel 2: per-relation dots — 2 adjacent relations per wave, natural order, NT stream
    {
        if (D == 768) {
            int nw = (R + 1) / 2;
            int grid = (nw + 3) / 4;
            relation_kernel2_t<768><<<grid, 256, 0, stream>>>(
                relation_emb, ctf8, sf8, W, counts, rel_start_idx, lt, R, 1.0f / CT_SCALE);
        } else {
            int grid = (R + 3) / 4;
            relation_kernel_gen<<<grid, 256, 0, stream>>>(
                relation_emb, ctf8, sf8, W, counts, rel_start_idx, lt, R, D, 1.0f / CT_SCALE);
        }
    }
    // Kernel 3+4 fused: segment softmax + final score (M waves)
    {
        int grid = (M + 3) / 4;
        if (D == 768) {
            score_fused_t<768><<<grid, 256, 0, stream>>>(
                neighbor_emb, W, b, start_idx, ew, lt, segs, sege, out, M);
        } else {
            score_fused_gen<<<grid, 256, 0, stream>>>(
                neighbor_emb, W, b, start_idx, ew, lt, segs, sege, out, M, D);
        }
    }
}